// Round 2
// baseline (784.023 us; speedup 1.0000x reference)
//
#include <hip/hip_runtime.h>
#include <hip/hip_bf16.h>

typedef unsigned int uint;
typedef unsigned short ushort;

constexpr int Bn = 256, Sn = 512, Vn = 32000, Dn = 100, Hn = 75, Ln = 128;
constexpr int HS = 80;  // h_all row stride in bf16 elements (160B, 16B-aligned)

// workspace layout (float units)
constexpr size_t OFF_EMBW = 0;                         // Vn*Hn floats = 2,400,000
constexpr size_t OFF_HALL = OFF_EMBW + (size_t)Vn*Hn;  // Bn*Sn*HS ushorts = 5,242,880 floats

__device__ __forceinline__ float bf2f(ushort u){ return __uint_as_float(((uint)u) << 16); }
__device__ __forceinline__ ushort f2bf(float f){
    union { __hip_bfloat16 h; ushort u; } v; v.h = __float2bfloat16(f); return v.u;
}
__device__ __forceinline__ float sigmoidf(float z){ return 1.f/(1.f + __expf(-z)); }

// ---------------------------------------------------------------------------
// embW[v][j] = sum_d emb[v][d]*W1[j][d] + b1[j] + b2[j]
// (projects the whole vocab: 4x less work than per-token; RNN input = gather)
// one wave per 64 vocab rows; lane = row; W1/b via wave-uniform s_loads
// ---------------------------------------------------------------------------
__global__ __launch_bounds__(64) void k_embproj(
    const float* __restrict__ emb, const float* __restrict__ W1,
    const float* __restrict__ b1, const float* __restrict__ b2,
    float* __restrict__ embW)
{
    const int lane = threadIdx.x;
    const int v = blockIdx.x*64 + lane;
    const float4* ev = (const float4*)(emb + (size_t)v*Dn);  // 400B/row, 16B-aligned
    float e[Dn];
    #pragma unroll
    for (int q = 0; q < Dn/4; ++q){
        float4 x = ev[q];
        e[4*q] = x.x; e[4*q+1] = x.y; e[4*q+2] = x.z; e[4*q+3] = x.w;
    }
    __shared__ float s_out[64*Hn];
    for (int j = 0; j < Hn; ++j){
        float a0 = b1[j] + b2[j], a1 = 0.f, a2 = 0.f, a3 = 0.f;
        const float* w = W1 + j*Dn;              // uniform -> scalar loads
        #pragma unroll
        for (int d = 0; d < Dn; d += 4){
            a0 += w[d]*e[d];     a1 += w[d+1]*e[d+1];
            a2 += w[d+2]*e[d+2]; a3 += w[d+3]*e[d+3];
        }
        s_out[lane*Hn + j] = (a0+a1) + (a2+a3);
    }
    __syncthreads();
    float* dst = embW + (size_t)blockIdx.x*64*Hn;
    for (int i = lane; i < 64*Hn; i += 64) dst[i] = s_out[i]; // coalesced
}

// ---------------------------------------------------------------------------
// Sequential scan: one block per batch row; only the h-update is in the loop.
// Thread j holds W2 row j in registers; h broadcast from LDS via float4.
// h_all stored bf16 (stride HS); o-projection hoisted to k_out.
// ---------------------------------------------------------------------------
__global__ __launch_bounds__(128) void k_rnn(
    const int* __restrict__ X, const float* __restrict__ W2,
    const float* __restrict__ embW, ushort* __restrict__ h_all)
{
    const int b = blockIdx.x;
    const int t = threadIdx.x;
    __shared__ int sX[Sn];
    __shared__ __align__(16) float hl[76];
    for (int i = t; i < Sn; i += 128) sX[i] = X[b*Sn + i];
    if (t < 76) hl[t] = 0.f;                    // h0 = zeros (+pad slot 75)
    const bool act = t < Hn;
    float w2r[76];
    if (act){
        #pragma unroll
        for (int k = 0; k < Hn; ++k) w2r[k] = W2[t*Hn + k];
    } else {
        #pragma unroll
        for (int k = 0; k < Hn; ++k) w2r[k] = 0.f;
    }
    w2r[75] = 0.f;
    __syncthreads();
    ushort* hout = h_all + (size_t)b*Sn*HS;
    float xpv = act ? embW[(size_t)sX[0]*Hn + t] : 0.f;
    for (int s = 0; s < Sn; ++s){
        float a0 = 0.f, a1 = 0.f, a2 = 0.f, a3 = 0.f;
        #pragma unroll
        for (int k = 0; k < 76; k += 4){        // 19x ds_read_b128 (broadcast)
            float4 hv = *(const float4*)(hl + k);
            a0 += w2r[k]*hv.x;   a1 += w2r[k+1]*hv.y;
            a2 += w2r[k+2]*hv.z; a3 += w2r[k+3]*hv.w;
        }
        float hn = sigmoidf(((a0+a1) + (a2+a3)) + xpv);
        // prefetch next step's gather while barriers drain
        int sn = (s < Sn-1) ? s+1 : s;
        float xpn = act ? embW[(size_t)sX[sn]*Hn + t] : 0.f;
        __syncthreads();                         // readers of hl done
        if (act){ hl[t] = hn; hout[s*HS + t] = f2bf(hn); }
        xpv = xpn;
        __syncthreads();                         // hl visible next step
    }
}

// ---------------------------------------------------------------------------
// Epilogue (fully parallel): per (b,s) row, o = sigmoid(h@Wo^T+bo),
// out = o@Wfc^T + bfc. One wave / 64 rows, lane = row.
// Weights via wave-uniform s_loads; o kept in LDS (stride 84, b128-aligned).
// ---------------------------------------------------------------------------
__global__ __launch_bounds__(64) void k_out(
    const ushort* __restrict__ h_all, const float* __restrict__ Wo,
    const float* __restrict__ bo, const float* __restrict__ Wfc,
    const float* __restrict__ bfc, float* __restrict__ out)
{
    const int lane = threadIdx.x;
    const size_t row = (size_t)blockIdx.x*64 + lane;
    const uint* hu = (const uint*)(h_all + row*HS); // 160B row, 4B-aligned
    float h[76];
    #pragma unroll
    for (int q = 0; q < 38; ++q){
        uint u = hu[q];
        h[2*q]   = __uint_as_float(u << 16);
        h[2*q+1] = __uint_as_float(u & 0xffff0000u);
    }

    __shared__ float o_lds[64*84];
    float* orow = o_lds + lane*84;               // 336B: 16B-aligned per lane

    for (int j = 0; j < Hn; ++j){
        float a0 = bo[j], a1 = 0.f, a2 = 0.f, a3 = 0.f;
        const float* w = Wo + j*Hn;              // uniform -> scalar loads
        #pragma unroll
        for (int k = 0; k < 72; k += 4){
            a0 += w[k]*h[k];     a1 += w[k+1]*h[k+1];
            a2 += w[k+2]*h[k+2]; a3 += w[k+3]*h[k+3];
        }
        a0 += w[72]*h[72]; a1 += w[73]*h[73]; a2 += w[74]*h[74];
        orow[j] = sigmoidf((a0+a1) + (a2+a3));
    }
    // single wave, per-lane LDS region: no barrier needed

    float* dst = out + row*Ln;
    for (int l0 = 0; l0 < Ln; l0 += 8){
        float acc[8];
        #pragma unroll
        for (int c = 0; c < 8; ++c) acc[c] = bfc[l0+c];
        #pragma unroll
        for (int k = 0; k < 72; k += 4){
            float4 ov = *(const float4*)(orow + k);
            #pragma unroll
            for (int c = 0; c < 8; ++c){
                const float* w = Wfc + (l0+c)*Hn;
                acc[c] += w[k]*ov.x + w[k+1]*ov.y + w[k+2]*ov.z + w[k+3]*ov.w;
            }
        }
        float o72 = orow[72], o73 = orow[73], o74 = orow[74];
        #pragma unroll
        for (int c = 0; c < 8; ++c){
            const float* w = Wfc + (l0+c)*Hn;
            acc[c] += w[72]*o72 + w[73]*o73 + w[74]*o74;
        }
        #pragma unroll
        for (int c = 0; c < 8; c += 4){
            float4 st; st.x = acc[c]; st.y = acc[c+1]; st.z = acc[c+2]; st.w = acc[c+3];
            *(float4*)(dst + l0 + c) = st;       // 16B aligned store
        }
    }
}

extern "C" void kernel_launch(void* const* d_in, const int* in_sizes, int n_in,
                              void* d_out, int out_size, void* d_ws, size_t ws_size,
                              hipStream_t stream)
{
    const int*   X   = (const int*)d_in[0];
    const float* emb = (const float*)d_in[1];
    const float* W1  = (const float*)d_in[2];
    const float* b1  = (const float*)d_in[3];
    const float* W2  = (const float*)d_in[4];
    const float* b2  = (const float*)d_in[5];
    const float* Wo  = (const float*)d_in[6];
    const float* bo  = (const float*)d_in[7];
    const float* Wfc = (const float*)d_in[8];
    const float* bfc = (const float*)d_in[9];
    float* out = (float*)d_out;
    float* ws  = (float*)d_ws;

    float*  embW = ws + OFF_EMBW;
    ushort* hall = (ushort*)(ws + OFF_HALL);

    k_embproj<<<dim3(Vn/64), dim3(64), 0, stream>>>(emb, W1, b1, b2, embW);
    k_rnn<<<dim3(Bn), dim3(128), 0, stream>>>(X, W2, embW, hall);
    k_out<<<dim3((Bn*Sn)/64), dim3(64), 0, stream>>>(hall, Wo, bo, Wfc, bfc, out);
}

// Round 3
// 448.448 us; speedup vs baseline: 1.7483x; 1.7483x over previous
//
#include <hip/hip_runtime.h>
#include <hip/hip_bf16.h>

typedef unsigned int uint;
typedef unsigned short ushort;

constexpr int Bn = 256, Sn = 512, Vn = 32000, Dn = 100, Hn = 75, Ln = 128;
constexpr int KP = 96;   // K padded for MFMA (3 x 32)

// workspace layout (float units, all offsets 16-float aligned)
constexpr size_t OFF_EMBW = 0;                             // Vn*Hn = 2,400,000 f
constexpr size_t OFF_HALL = OFF_EMBW + (size_t)Vn*Hn;      // 131072*96 ush = 6,291,456 f
constexpr size_t OFF_WOH  = OFF_HALL + (size_t)Bn*Sn*KP/2; // 80*96 ush = 3840 f
constexpr size_t OFF_WOL  = OFF_WOH + 3840;
constexpr size_t OFF_WFH  = OFF_WOL + 3840;                // 128*96 ush = 6144 f
constexpr size_t OFF_WFL  = OFF_WFH + 6144;
constexpr size_t OFF_BFC  = OFF_WFL + 6144;                // 128 f

typedef __attribute__((ext_vector_type(8))) short short8;   // 8 bf16 (4 VGPRs)
typedef __attribute__((ext_vector_type(4))) float floatx4;  // MFMA C/D

__device__ __forceinline__ float bf2f(ushort u){ return __uint_as_float(((uint)u) << 16); }
__device__ __forceinline__ ushort f2bf(float f){
    union { __hip_bfloat16 h; ushort u; } v; v.h = __float2bfloat16(f); return v.u;
}
__device__ __forceinline__ float sigmoidf(float z){ return 1.f/(1.f + __expf(-z)); }

// raw barrier: does NOT drain vmcnt (global prefetch/stores stay in flight)
__device__ __forceinline__ void bar_raw(){ asm volatile("s_barrier" ::: "memory"); }
// barrier with LDS-only drain (my ds_write visible to the other wave)
__device__ __forceinline__ void bar_lds(){ asm volatile("s_waitcnt lgkmcnt(0)\ns_barrier" ::: "memory"); }

// ---------------------------------------------------------------------------
// Weight prep: pad Wo->80x96, Wfc->128x96, split fp32 into bf16 hi+lo pairs.
// ---------------------------------------------------------------------------
__global__ __launch_bounds__(256) void k_wprep(
    const float* __restrict__ Wo, const float* __restrict__ Wfc,
    const float* __restrict__ bfc, ushort* __restrict__ woh, ushort* __restrict__ wol,
    ushort* __restrict__ wfh, ushort* __restrict__ wfl, float* __restrict__ bfcp)
{
    const int tid = blockIdx.x*256 + threadIdx.x;
    const int stride = gridDim.x*256;
    for (int i = tid; i < 80*KP; i += stride){
        int n = i / KP, k = i % KP;
        float v = (n < Hn && k < Hn) ? Wo[n*Hn + k] : 0.f;
        ushort h = f2bf(v);
        woh[i] = h; wol[i] = f2bf(v - bf2f(h));
    }
    for (int i = tid; i < Ln*KP; i += stride){
        int l = i / KP, k = i % KP;
        float v = (k < Hn) ? Wfc[l*Hn + k] : 0.f;
        ushort h = f2bf(v);
        wfh[i] = h; wfl[i] = f2bf(v - bf2f(h));
    }
    for (int i = tid; i < Ln; i += stride) bfcp[i] = bfc[i];
}

// ---------------------------------------------------------------------------
// embW[v][j] = sum_d emb[v][d]*W1[j][d] + b1[j] + b2[j]  (whole vocab: 4x less
// work than per-token). One wave / 64 vocab rows; W1 via wave-uniform s_loads.
// ---------------------------------------------------------------------------
__global__ __launch_bounds__(64) void k_embproj(
    const float* __restrict__ emb, const float* __restrict__ W1,
    const float* __restrict__ b1, const float* __restrict__ b2,
    float* __restrict__ embW)
{
    const int lane = threadIdx.x;
    const int v = blockIdx.x*64 + lane;
    const float4* ev = (const float4*)(emb + (size_t)v*Dn);
    float e[Dn];
    #pragma unroll
    for (int q = 0; q < Dn/4; ++q){
        float4 x = ev[q];
        e[4*q] = x.x; e[4*q+1] = x.y; e[4*q+2] = x.z; e[4*q+3] = x.w;
    }
    __shared__ float s_out[64*Hn];
    for (int j = 0; j < Hn; ++j){
        float a0 = b1[j] + b2[j], a1 = 0.f, a2 = 0.f, a3 = 0.f;
        const float* w = W1 + j*Dn;
        #pragma unroll
        for (int d = 0; d < Dn; d += 4){
            a0 += w[d]*e[d];     a1 += w[d+1]*e[d+1];
            a2 += w[d+2]*e[d+2]; a3 += w[d+3]*e[d+3];
        }
        s_out[lane*Hn + j] = (a0+a1) + (a2+a3);
    }
    __syncthreads();
    float* dst = embW + (size_t)blockIdx.x*64*Hn;
    for (int i = lane; i < 64*Hn; i += 64) dst[i] = s_out[i];
}

// ---------------------------------------------------------------------------
// Sequential scan, one block (2 waves) per batch row. fp32 recurrence.
// Raw s_barrier (lgkm-only drain): embW prefetch (2 steps ahead) and hout
// stores stay in flight across barriers -> no vmcnt drain per step.
// h stored bf16, row stride KP=96 with zeroed pad cols (MFMA K-padding).
// ---------------------------------------------------------------------------
__global__ __launch_bounds__(128) void k_rnn(
    const int* __restrict__ X, const float* __restrict__ W2,
    const float* __restrict__ embW, ushort* __restrict__ h_all)
{
    const int b = blockIdx.x;
    const int t = threadIdx.x;
    __shared__ int sX[Sn];
    __shared__ __align__(16) float hl[76];
    for (int i = t; i < Sn; i += 128) sX[i] = X[b*Sn + i];
    if (t < 76) hl[t] = 0.f;                 // h0 = 0 (+pad slot 75)
    const bool act = t < Hn;
    float w2r[76];
    if (act){
        #pragma unroll
        for (int k = 0; k < Hn; ++k) w2r[k] = W2[t*Hn + k];
    } else {
        #pragma unroll
        for (int k = 0; k < Hn; ++k) w2r[k] = 0.f;
    }
    w2r[75] = 0.f;
    __syncthreads();
    ushort* hout = h_all + (size_t)b*Sn*KP;
    float xpc = act ? embW[(size_t)sX[0]*Hn + t] : 0.f;
    float xpn = act ? embW[(size_t)sX[1]*Hn + t] : 0.f;
    for (int s = 0; s < Sn; ++s){
        float a0 = 0.f, a1 = 0.f, a2 = 0.f, a3 = 0.f;
        #pragma unroll
        for (int k = 0; k < 76; k += 4){     // 19x ds_read_b128, broadcast
            float4 hv = *(const float4*)(hl + k);
            a0 += w2r[k]*hv.x;   a1 += w2r[k+1]*hv.y;
            a2 += w2r[k+2]*hv.z; a3 += w2r[k+3]*hv.w;
        }
        float hn = sigmoidf(((a0+a1) + (a2+a3)) + xpc);
        int sn = (s+2 < Sn) ? s+2 : Sn-1;
        float xp2 = act ? embW[(size_t)sX[sn]*Hn + t] : 0.f;  // 2-ahead prefetch
        bar_raw();                            // hl readers done (data-dep drained)
        if (act) hl[t] = hn;
        if (t < KP) hout[(size_t)s*KP + t] = act ? f2bf(hn) : (ushort)0;
        bar_lds();                            // lgkm drain only; vmem in flight
        xpc = xpn; xpn = xp2;
    }
}

// ---------------------------------------------------------------------------
// Epilogue GEMM via MFMA 16x16x32 bf16, hi+lo weight split (fp32-grade weights)
// Per block: 4 waves x 16 rows. Phase1: Z = H(16x96)@Wo^T + bo -> sigmoid ->
// O bf16 in LDS (row stride 104, 2-way-free banks); Phase2: OUT = O@Wfc^T+bfc.
// A/B frag: row = lane&15, k = (lane>>4)*8+j (gemm_bt, m91-verified).
// C/D frag: col = lane&15, row = (lane>>4)*4+reg (m89-verified).
// ---------------------------------------------------------------------------
__global__ __launch_bounds__(256) void k_out(
    const ushort* __restrict__ h_all, const ushort* __restrict__ woh,
    const ushort* __restrict__ wol, const ushort* __restrict__ wfh,
    const ushort* __restrict__ wfl, const float* __restrict__ bfcp,
    const float* __restrict__ bo, float* __restrict__ out)
{
    const int lane = threadIdx.x & 63;
    const int w    = threadIdx.x >> 6;
    const size_t r0 = (size_t)blockIdx.x*64 + w*16;
    const int m = lane & 15;
    const int g = lane >> 4;
    __shared__ __align__(16) ushort o_lds[4][16*104];
    ushort* ot = o_lds[w];
    // zero O pad cols 80..95 (read by k-step 2); wave-local, no barrier needed
    for (int i = lane; i < 128; i += 64){
        int row = i >> 3, cw = i & 7;
        *(uint*)&ot[row*104 + 80 + cw*2] = 0u;
    }
    // ---- Phase 1: Z = H @ Wo^T (hi+lo) ----
    floatx4 acc1[5] = {};
    const ushort* hbase = h_all + r0*KP;
    #pragma unroll
    for (int ks = 0; ks < 3; ++ks){
        short8 a = *(const short8*)(hbase + (size_t)m*KP + ks*32 + g*8);
        #pragma unroll
        for (int t = 0; t < 5; ++t){
            short8 bh = *(const short8*)(woh + (16*t + m)*KP + ks*32 + g*8);
            short8 bl = *(const short8*)(wol + (16*t + m)*KP + ks*32 + g*8);
            acc1[t] = __builtin_amdgcn_mfma_f32_16x16x32_bf16(a, bh, acc1[t], 0, 0, 0);
            acc1[t] = __builtin_amdgcn_mfma_f32_16x16x32_bf16(a, bl, acc1[t], 0, 0, 0);
        }
    }
    // ---- bo + sigmoid, O -> LDS bf16 (C layout) ----
    #pragma unroll
    for (int t = 0; t < 5; ++t){
        int n = 16*t + m;
        float bias = (n < Hn) ? bo[n] : 0.f;
        #pragma unroll
        for (int r = 0; r < 4; ++r){
            int row = g*4 + r;
            float o = sigmoidf(acc1[t][r] + bias);
            if (n >= Hn) o = 0.f;       // Wo pad rows give z=0 -> 0.5; kill
            ot[row*104 + n] = f2bf(o);
        }
    }
    // wave-local LDS RAW: DS pipe is in-order within a wave; no barrier
    // ---- Phase 2: OUT = O @ Wfc^T (hi+lo) ----
    floatx4 acc2[8] = {};
    #pragma unroll
    for (int ks = 0; ks < 3; ++ks){
        short8 a = *(const short8*)(ot + m*104 + ks*32 + g*8);
        #pragma unroll
        for (int t = 0; t < 8; ++t){
            short8 bh = *(const short8*)(wfh + (16*t + m)*KP + ks*32 + g*8);
            short8 bl = *(const short8*)(wfl + (16*t + m)*KP + ks*32 + g*8);
            acc2[t] = __builtin_amdgcn_mfma_f32_16x16x32_bf16(a, bh, acc2[t], 0, 0, 0);
            acc2[t] = __builtin_amdgcn_mfma_f32_16x16x32_bf16(a, bl, acc2[t], 0, 0, 0);
        }
    }
    // ---- bfc + store ----
    float* orow = out + r0*Ln;
    #pragma unroll
    for (int t = 0; t < 8; ++t){
        float bias = bfcp[16*t + m];
        #pragma unroll
        for (int r = 0; r < 4; ++r){
            int row = g*4 + r;
            orow[(size_t)row*Ln + 16*t + m] = acc2[t][r] + bias;
        }
    }
}

extern "C" void kernel_launch(void* const* d_in, const int* in_sizes, int n_in,
                              void* d_out, int out_size, void* d_ws, size_t ws_size,
                              hipStream_t stream)
{
    const int*   X   = (const int*)d_in[0];
    const float* emb = (const float*)d_in[1];
    const float* W1  = (const float*)d_in[2];
    const float* b1  = (const float*)d_in[3];
    const float* W2  = (const float*)d_in[4];
    const float* b2  = (const float*)d_in[5];
    const float* Wo  = (const float*)d_in[6];
    const float* bo  = (const float*)d_in[7];
    const float* Wfc = (const float*)d_in[8];
    const float* bfc = (const float*)d_in[9];
    float* out = (float*)d_out;
    float* ws  = (float*)d_ws;

    float*  embW = ws + OFF_EMBW;
    ushort* hall = (ushort*)(ws + OFF_HALL);
    ushort* woh  = (ushort*)(ws + OFF_WOH);
    ushort* wol  = (ushort*)(ws + OFF_WOL);
    ushort* wfh  = (ushort*)(ws + OFF_WFH);
    ushort* wfl  = (ushort*)(ws + OFF_WFL);
    float*  bfcp = ws + OFF_BFC;

    k_wprep<<<dim3(48), dim3(256), 0, stream>>>(Wo, Wfc, bfc, woh, wol, wfh, wfl, bfcp);
    k_embproj<<<dim3(Vn/64), dim3(64), 0, stream>>>(emb, W1, b1, b2, embW);
    k_rnn<<<dim3(Bn), dim3(128), 0, stream>>>(X, W2, embW, hall);
    k_out<<<dim3((Bn*Sn)/64), dim3(256), 0, stream>>>(hall, woh, wol, wfh, wfl, bfcp, bo, out);
}